// Round 7
// baseline (71.453 us; speedup 1.0000x reference)
//
#include <hip/hip_runtime.h>
#include <hip/hip_bf16.h>

// PatchExtractor3d: out[b, c*27 + i*9 + j*3 + l, d, h, w] = x_pad[b, c, d+i-1, h+j-1, w+l-1]
// x: (2, 3, 32, 128, 128) f32 ; out: (2, 81, 32, 128, 128) f32 (339.7 MB written)
//
// R6: maximally fill-like store stream. wave-task = (output channel, d-plane):
// each wave issues 64 back-to-back 1KB-contiguous nt stores = one linear 64KB
// walk, never hopping streams. (i,j,l) are block-uniform -> scalar-branch l
// specialization. Loads are 1:1 with stores but L1/L2-served (each input plane
// re-read by 27 channel-waves; dq = bid&7 XCD-pins d-chunks so per-XCD input
// working set ~2.25MB < 4MB L2). Low VGPR -> high occupancy, smooth issue.

#define B_  2
#define C_  3
#define D_  32
#define H_  128
#define W_  128
#define HW_ (H_ * W_)
#define CHW ((size_t)(D_ * H_ * W_))   // 524288 floats per output channel

typedef float f32x4 __attribute__((ext_vector_type(4)));

template<int L>
__device__ __forceinline__ void emit_plane(const float* __restrict__ srcp,
                                           bool dok, int j, int w4, int hpar,
                                           float* __restrict__ dst) {
    if (!dok) {
        const f32x4 z = (f32x4){0.f, 0.f, 0.f, 0.f};
#pragma unroll 8
        for (int k = 0; k < 64; ++k)
            __builtin_nontemporal_store(z, reinterpret_cast<f32x4*>(dst + k * 256));
        return;
    }
#pragma unroll 8
    for (int k = 0; k < 64; ++k) {
        const int hp = 2 * k + hpar + j - 1;       // source row for output row 2k+hpar
        f32x4 v = (f32x4){0.f, 0.f, 0.f, 0.f};
        if ((unsigned)hp < (unsigned)H_)
            v = *reinterpret_cast<const f32x4*>(srcp + (size_t)hp * W_ + w4 * 4);
        f32x4 o;
        if (L == 1) {
            o = v;
        } else {
            // w-edges from neighbor lanes; cross-half leak (lane 31<->32) lands
            // exactly on the masked w4==0 / w4==31 pad-zero positions.
            if (L == 0) {
                float le = __shfl_up(v.w, 1, 64);
                if (w4 == 0) le = 0.f;
                o = (f32x4){le, v.x, v.y, v.z};
            } else {
                float ri = __shfl_down(v.x, 1, 64);
                if (w4 == 31) ri = 0.f;
                o = (f32x4){v.y, v.z, v.w, ri};
            }
        }
        // k*256 floats = 1KB: 64 consecutive wave-stores walk 64KB linearly
        __builtin_nontemporal_store(o, reinterpret_cast<f32x4*>(dst + k * 256));
    }
}

__global__ __launch_bounds__(256) void patch3d_kernel(const float* __restrict__ x,
                                                      float* __restrict__ out) {
    const int bid = blockIdx.x;          // 0..1295
    const int ch  = bid >> 3;            // 0..161: global output channel (bc*27+co)
    const int dq  = bid & 7;             // d-chunk -> XCD (round-robin)
    const int bc  = ch / 27;             // b*3 + c
    const int co  = ch - bc * 27;
    const int i   = co / 9;
    const int j   = (co / 3) % 3;
    const int l   = co % 3;

    const int wave = threadIdx.x >> 6;   // 0..3 -> d within chunk
    const int lane = threadIdx.x & 63;
    const int w4   = lane & 31;          // float4 index in W
    const int hpar = lane >> 5;          // row parity within each 1KB store
    const int d    = dq * 4 + wave;

    const int  dp  = d + i - 1;
    const bool dok = (unsigned)dp < (unsigned)D_;

    const float* __restrict__ srcp =
        x + (size_t)bc * CHW + (size_t)(dok ? dp : 0) * HW_;
    float* __restrict__ dst = out + (size_t)ch * CHW + (size_t)d * HW_
                                  + hpar * W_ + w4 * 4;

    switch (l) {   // block-uniform -> scalar branch
        case 0:  emit_plane<0>(srcp, dok, j, w4, hpar, dst); break;
        case 1:  emit_plane<1>(srcp, dok, j, w4, hpar, dst); break;
        default: emit_plane<2>(srcp, dok, j, w4, hpar, dst); break;
    }
}

extern "C" void kernel_launch(void* const* d_in, const int* in_sizes, int n_in,
                              void* d_out, int out_size, void* d_ws, size_t ws_size,
                              hipStream_t stream) {
    const float* x = (const float*)d_in[0];
    float* out = (float*)d_out;

    // 162 channels x 8 d-chunks = 1296 blocks; 4 waves/block = one d-plane each
    dim3 grid(1296, 1, 1);
    dim3 block(256, 1, 1);
    patch3d_kernel<<<grid, block, 0, stream>>>(x, out);
}

// Round 8
// 67.630 us; speedup vs baseline: 1.0565x; 1.0565x over previous
//
#include <hip/hip_runtime.h>
#include <hip/hip_bf16.h>

// PatchExtractor3d: out[b, c*27 + i*9 + j*3 + l, d, h, w] = x_pad[b, c, d+i-1, h+j-1, w+l-1]
// x: (2, 3, 32, 128, 128) f32 ; out: (2, 81, 32, 128, 128) f32 (339.7 MB written)
//
// FINAL (revert to best-measured, R2 structure, 66.6 us ~ 5.1 TB/s write):
// each thread owns 4 output rows (h = h0 + 2k, k=0..3; wave lane bit5 =
// h-parity), so per channel the wave issues 4 consecutive dwordx4 stores
// covering a contiguous 4KB burst (k*1024B folds into the store immediate ->
// one address reg per channel). Block covers 32 consecutive h rows -> 16KB
// contiguous per channel per block. 9 row-loads per d-plane are reused across
// the (j,k) overlap: 27 loads + 54 shuffles per 108 stores per thread.
//
// Falsified levers (all within +-3us or worse): stream count 27->9->1,
// burst 1->4->8->64KB, nontemporal stores, XCD-pinned d-chunks. The op is
// ~95% pure HBM write; 340MB at fill-calibrated 6.9TB/s + ~7us overhead
// gives a ~62us floor; 66.6us is within ~7% -> practical roofline.

#define B_  2
#define C_  3
#define D_  32
#define H_  128
#define W_  128
#define CHW ((size_t)(D_ * H_ * W_))   // 524288 floats per output channel

__global__ __launch_bounds__(256) void patch3d_kernel(const float* __restrict__ x,
                                                      float* __restrict__ out) {
    const int bc = blockIdx.y;                  // b*3 + c (block-uniform)
    const int t  = blockIdx.x * 256 + threadIdx.x;

    const int w4   = t & 31;                    // float4 index in W (32)
    const int hpar = (t >> 5) & 1;              // h parity (lane bit 5)
    const int hsup = (t >> 6) & 15;             // 8-row supergroup
    const int d    = t >> 10;                   // 0..31 (block-uniform)

    const int h0       = hsup * 8 + hpar;       // first output row; rows h0+2k, k=0..3
    const int base_row = h0 - 1;                // source rows R[m] = base_row + m, m=0..8

    const float* __restrict__ src = x + (size_t)bc * CHW;
    float* __restrict__ dstc = out + (size_t)bc * 27 * CHW
                                   + (size_t)d * (H_ * W_) + (size_t)h0 * W_ + w4 * 4;

#pragma unroll
    for (int i = 0; i < 3; ++i) {
        const int dp = d + i - 1;

        float4 R[9]; float le[9], ri[9];
#pragma unroll
        for (int m = 0; m < 9; ++m) {
            const int hp = base_row + m;
            float4 v = make_float4(0.f, 0.f, 0.f, 0.f);
            if (((unsigned)dp < (unsigned)D_) & ((unsigned)hp < (unsigned)H_)) {
                v = *reinterpret_cast<const float4*>(src + ((size_t)dp * H_ + hp) * W_ + w4 * 4);
            }
            // w-edges from neighbor lanes; cross-parity leak lands exactly on
            // the masked w4==0 / w4==31 lanes (pad-zero positions).
            float l_ = __shfl_up(v.w, 1, 64);
            float r_ = __shfl_down(v.x, 1, 64);
            if (w4 == 0)  l_ = 0.f;
            if (w4 == 31) r_ = 0.f;
            R[m] = v; le[m] = l_; ri[m] = r_;
        }

#pragma unroll
        for (int j = 0; j < 3; ++j) {
#pragma unroll
            for (int l = 0; l < 3; ++l) {
                float* p = dstc + (size_t)(i * 9 + j * 3 + l) * CHW;
#pragma unroll
                for (int k = 0; k < 4; ++k) {
                    const int m = 2 * k + j;           // source row for output h0+2k
                    const float4 v = R[m];
                    float4 o;
                    if (l == 0)      o = make_float4(le[m], v.x, v.y, v.z);
                    else if (l == 1) o = v;
                    else             o = make_float4(v.y, v.z, v.w, ri[m]);
                    // k*256 floats = 1024B: folds into the store immediate
                    *reinterpret_cast<float4*>(p + k * 256) = o;
                }
            }
        }
    }
}

extern "C" void kernel_launch(void* const* d_in, const int* in_sizes, int n_in,
                              void* d_out, int out_size, void* d_ws, size_t ws_size,
                              hipStream_t stream) {
    const float* x = (const float*)d_in[0];
    float* out = (float*)d_out;

    // per (b,c): 32(w4) x 2(hpar) x 16(hsup) x 32(d) = 32768 threads = 128 blocks
    dim3 grid(128, B_ * C_, 1);
    dim3 block(256, 1, 1);
    patch3d_kernel<<<grid, block, 0, stream>>>(x, out);
}